// Round 8
// baseline (91.113 us; speedup 1.0000x reference)
//
#include <hip/hip_runtime.h>
#include <hip/hip_fp16.h>
#include <math.h>

// StripePolynomial2d, round 8 (R7 fixed): R6 + 4 pixels/thread + NT stores.
// - Single persistent dispatch, coeff table built in LDS per block (as R6).
// - Each thread handles 4 consecutive-h pixels sequentially: float4 global IO
//   (VMEM instr /4), setup amortized, same per-pixel arithmetic (bit-identical
//   to R4/R6: absmax 0.015625).
// - NT store via clang ext_vector_type (HIP float4 is rejected by the builtin).
// Record layout (32 B per (ec,seg)):
//   [c0_0,c0_1][c1_0,c1_1][c2_0,c2_1][c0_2,c1_2][c2_2,0] + 12 B pad.

#define NREC 576              // 9 ec * 64 seg

typedef float vfloat4 __attribute__((ext_vector_type(4)));

__device__ __forceinline__ __half2 u2h2(unsigned int u) {
    __half2 h; __builtin_memcpy(&h, &u, 4); return h;
}
__device__ __forceinline__ unsigned int h22u(__half2 h) {
    unsigned int u; __builtin_memcpy(&u, &h, 4); return u;
}

__device__ __forceinline__ void coeff_compute(const float* __restrict__ Wt, int r,
                                              unsigned int rec[8]) {
    int ec  = r >> 6;
    int seg = r & 63;
    int e   = ec / 3;
    int c   = ec - e * 3;
    int nb  = 2 * seg;
    float c0[3], c1[3], c2[3];
    #pragma unroll
    for (int o = 0; o < 3; ++o) {
        float w0, w1, w2;
        if (e == 0) {
            const float* p0 = Wt + ((0 * 3 + o) * 3 + c) * 129 + nb;
            const float* p1 = Wt + ((1 * 3 + o) * 3 + c) * 129 + nb;
            w0 = p0[0] + p1[0]; w1 = p0[1] + p1[1]; w2 = p0[2] + p1[2];
        } else {
            const float* p = Wt + (((e + 1) * 3 + o) * 3 + c) * 129 + nb;
            w0 = p[0]; w1 = p[1]; w2 = p[2];
        }
        c0[o] = 0.25f  * w1;
        c1[o] = 0.125f * (w2 - w0);
        c2[o] = 0.125f * (w0 + w2) - 0.25f * w1;
    }
    rec[0] = h22u(__floats2half2_rn(c0[0], c0[1]));
    rec[1] = h22u(__floats2half2_rn(c1[0], c1[1]));
    rec[2] = h22u(__floats2half2_rn(c2[0], c2[1]));
    rec[3] = h22u(__floats2half2_rn(c0[2], c1[2]));
    rec[4] = h22u(__floats2half2_rn(c2[2], 0.0f));
    rec[5] = 0u; rec[6] = 0u; rec[7] = 0u;
}

__global__ __launch_bounds__(256) void stripe_all(
    const float* __restrict__ x, const float* __restrict__ Wt,
    float* __restrict__ out)
{
    __shared__ uint4 lw4[NREC * 2];   // 18432 B
    const unsigned int* lw = (const unsigned int*)lw4;
    const int tid = threadIdx.x;

    // ---- build coeff table once per block ----
    for (int r = tid; r < NREC; r += 256) {
        unsigned int rec[8];
        coeff_compute(Wt, r, rec);
        lw4[2 * r]     = make_uint4(rec[0], rec[1], rec[2], rec[3]);
        lw4[2 * r + 1] = make_uint4(rec[4], rec[5], rec[6], rec[7]);
    }
    __syncthreads();

    // q_e = pos_e/8 + 32, f32 from compile-time f64 constants.
    constexpr double RATIO = 512.0 / 513.0;
    constexpr double CX = 0x1.6a09e667f3bcdp-1;  // cos(f64 pi/4)
    constexpr double SY = 0x1.6a09e667f3bccp-1;  // sin(f64 pi/4), 1 ulp lower
    constexpr double S0 = RATIO * 64.0 / 511.0;
    constexpr double R2MAX = CX * 511.0 + SY * 511.0;
    constexpr double S2 = RATIO * 64.0 / R2MAX;
    constexpr double MN3 = -(SY * 511.0);
    constexpr double MX3 = CX * 511.0;
    constexpr double S3 = RATIO * 64.0 / (MX3 - MN3);

    // block -> 1024 consecutive pixels of one image; thread -> 4 consecutive h
    const int b  = blockIdx.x >> 8;
    const int p0 = ((blockIdx.x & 255) << 10) + (tid << 2);
    const int w  = p0 >> 9;

    const float wf = (float)w;
    const float q0   = wf * (float)S0;
    const float wcx2 = wf * (float)(CX * S2);
    const float wcx3 = fmaf(wf, (float)(CX * S3), (float)(-MN3 * S3));

    const int base = ((b * 3) << 18) + p0;
    float4 xv[3];
    #pragma unroll
    for (int c = 0; c < 3; ++c)
        xv[c] = *(const float4*)(x + base + (c << 18));

    vfloat4 oacc[3];

    #pragma unroll
    for (int k = 0; k < 4; ++k) {
        const float hf = (float)((p0 & 511) + k);
        float qe[3];
        qe[0] = q0;
        qe[1] = fmaf(hf, (float)(SY * S2), wcx2);
        qe[2] = fmaf(hf, (float)(-(SY * S3)), wcx3);

        const float xc[3] = {
            k == 0 ? xv[0].x : k == 1 ? xv[0].y : k == 2 ? xv[0].z : xv[0].w,
            k == 0 ? xv[1].x : k == 1 ? xv[1].y : k == 2 ? xv[1].z : xv[1].w,
            k == 0 ? xv[2].x : k == 1 ? xv[2].y : k == 2 ? xv[2].z : xv[2].w };

        // ---- Phase A: all 9 (seg, xl) ----
        int   segi[9];
        float xls[9];
        #pragma unroll
        for (int s = 0; s < 9; ++s) {
            int e = s / 3, c = s - 3 * (s / 3);
            float tn   = fmaf(xc[c], 0.125f, qe[e]);
            float segf = fminf(fmaxf(floorf(tn), 0.0f), 63.0f);
            segi[s] = (int)segf;
            xls[s]  = fmaf(tn - segf, 2.0f, -1.0f);
        }

        // ---- Phase B: batch all LDS reads ----
        uint4        A[9];
        unsigned int Bv[9];
        #pragma unroll
        for (int s = 0; s < 9; ++s) {
            const unsigned int* rp = lw + ((s * 64 + segi[s]) << 3);
            A[s]  = *(const uint4*)rp;   // ds_read_b128
            Bv[s] = rp[4];               // ds_read_b32
        }

        // ---- Phase C: convert + Horner + accumulate ----
        float acc0 = 0.f, acc1 = 0.f, acc2 = 0.f;
        #pragma unroll
        for (int s = 0; s < 9; ++s) {
            float  xl  = xls[s];
            float2 k0 = __half22float2(u2h2(A[s].x));  // c0_0, c0_1
            float2 k1 = __half22float2(u2h2(A[s].y));  // c1_0, c1_1
            float2 k2 = __half22float2(u2h2(A[s].z));  // c2_0, c2_1
            float2 k3 = __half22float2(u2h2(A[s].w));  // c0_2, c1_2
            float  c22 = __half2float(__low2half(u2h2(Bv[s])));
            acc0 += fmaf(fmaf(k2.x, xl, k1.x), xl, k0.x);
            acc1 += fmaf(fmaf(k2.y, xl, k1.y), xl, k0.y);
            acc2 += fmaf(fmaf(c22,  xl, k3.y), xl, k3.x);
        }

        oacc[0][k] = acc0; oacc[1][k] = acc1; oacc[2][k] = acc2;
    }

    #pragma unroll
    for (int o = 0; o < 3; ++o)
        __builtin_nontemporal_store(oacc[o], (vfloat4*)(out + base + (o << 18)));
}

extern "C" void kernel_launch(void* const* d_in, const int* in_sizes, int n_in,
                              void* d_out, int out_size, void* d_ws, size_t ws_size,
                              hipStream_t stream) {
    const float* x  = (const float*)d_in[0]; // [8,3,512,512]
    const float* Wt = (const float*)d_in[1]; // [4,3,3,129]
    float* out = (float*)d_out;              // [8,3,512,512]

    hipLaunchKernelGGL(stripe_all, dim3(2048), dim3(256), 0, stream, x, Wt, out);
}

// Round 9
// 83.421 us; speedup vs baseline: 1.0922x; 1.0922x over previous
//
#include <hip/hip_runtime.h>
#include <hip/hip_fp16.h>
#include <math.h>

// StripePolynomial2d, round 9: R6 structure at forced full occupancy.
// - __launch_bounds__(256,8): VGPR capped at 64 -> 8 waves/SIMD, 8 blocks/CU.
// - No batch arrays: each step fuses seg/xl -> ds_read_b128+b32 -> Horner;
//   compiler pipelines within the register budget.
// - Split LDS tables: lwA[576] uint4 (16B recs: c0_01,c1_01,c2_01,c0c1_2),
//   lwB[576] uint (c2_2) -> 11520 B total.
// - Arithmetic identical to R6: absmax must stay 0.015625.

#define NREC 576              // 9 ec * 64 seg
#define NTILE 8192            // 8 imgs * 1024 tiles
#define NBLK 2048

__device__ __forceinline__ __half2 u2h2(unsigned int u) {
    __half2 h; __builtin_memcpy(&h, &u, 4); return h;
}
__device__ __forceinline__ unsigned int h22u(__half2 h) {
    unsigned int u; __builtin_memcpy(&u, &h, 4); return u;
}

__device__ __forceinline__ void coeff_compute(const float* __restrict__ Wt, int r,
                                              uint4& a, unsigned int& bb) {
    int ec  = r >> 6;
    int seg = r & 63;
    int e   = ec / 3;
    int c   = ec - e * 3;
    int nb  = 2 * seg;
    float c0[3], c1[3], c2[3];
    #pragma unroll
    for (int o = 0; o < 3; ++o) {
        float w0, w1, w2;
        if (e == 0) {
            const float* p0 = Wt + ((0 * 3 + o) * 3 + c) * 129 + nb;
            const float* p1 = Wt + ((1 * 3 + o) * 3 + c) * 129 + nb;
            w0 = p0[0] + p1[0]; w1 = p0[1] + p1[1]; w2 = p0[2] + p1[2];
        } else {
            const float* p = Wt + (((e + 1) * 3 + o) * 3 + c) * 129 + nb;
            w0 = p[0]; w1 = p[1]; w2 = p[2];
        }
        c0[o] = 0.25f  * w1;
        c1[o] = 0.125f * (w2 - w0);
        c2[o] = 0.125f * (w0 + w2) - 0.25f * w1;
    }
    a.x = h22u(__floats2half2_rn(c0[0], c0[1]));
    a.y = h22u(__floats2half2_rn(c1[0], c1[1]));
    a.z = h22u(__floats2half2_rn(c2[0], c2[1]));
    a.w = h22u(__floats2half2_rn(c0[2], c1[2]));
    bb  = h22u(__floats2half2_rn(c2[2], 0.0f));
}

__global__ __launch_bounds__(256, 8) void stripe_all(
    const float* __restrict__ x, const float* __restrict__ Wt,
    float* __restrict__ out)
{
    __shared__ uint4        lwA[NREC];   // 9216 B
    __shared__ unsigned int lwB[NREC];   // 2304 B
    const int tid = threadIdx.x;

    // ---- build coeff table once per block ----
    for (int r = tid; r < NREC; r += 256) {
        uint4 a; unsigned int bb;
        coeff_compute(Wt, r, a, bb);
        lwA[r] = a;
        lwB[r] = bb;
    }
    __syncthreads();

    // q_e = pos_e/8 + 32, f32 from compile-time f64 constants.
    constexpr double RATIO = 512.0 / 513.0;
    constexpr double CX = 0x1.6a09e667f3bcdp-1;  // cos(f64 pi/4)
    constexpr double SY = 0x1.6a09e667f3bccp-1;  // sin(f64 pi/4), 1 ulp lower
    constexpr double S0 = RATIO * 64.0 / 511.0;
    constexpr double R2MAX = CX * 511.0 + SY * 511.0;
    constexpr double S2 = RATIO * 64.0 / R2MAX;
    constexpr double MN3 = -(SY * 511.0);
    constexpr double MX3 = CX * 511.0;
    constexpr double S3 = RATIO * 64.0 / (MX3 - MN3);

    for (int t = blockIdx.x; t < NTILE; t += NBLK) {
        const int b = t >> 10;
        const int p = ((t & 1023) << 8) + tid;
        const int w = p >> 9;
        const int h = p & 511;

        const float wf = (float)w, hf = (float)h;
        float qe[3];
        qe[0] = wf * (float)S0;
        qe[1] = fmaf(hf, (float)(SY * S2), wf * (float)(CX * S2));
        qe[2] = fmaf(hf, (float)(-(SY * S3)),
                     fmaf(wf, (float)(CX * S3), (float)(-MN3 * S3)));

        const int xbase = ((b * 3) << 18) + p;
        float xv[3];
        xv[0] = x[xbase];
        xv[1] = x[xbase + (1 << 18)];
        xv[2] = x[xbase + (2 << 18)];

        float acc0 = 0.f, acc1 = 0.f, acc2 = 0.f;

        #pragma unroll
        for (int s = 0; s < 9; ++s) {
            const int e = s / 3, c = s - 3 * (s / 3);
            float tn   = fmaf(xv[c], 0.125f, qe[e]);
            float segf = fminf(fmaxf(floorf(tn), 0.0f), 63.0f);
            int   seg  = (int)segf;
            float xl   = fmaf(tn - segf, 2.0f, -1.0f);

            const int  ri = s * 64 + seg;
            uint4        A  = lwA[ri];   // ds_read_b128
            unsigned int Bv = lwB[ri];   // ds_read_b32

            float2 k0 = __half22float2(u2h2(A.x));  // c0_0, c0_1
            float2 k1 = __half22float2(u2h2(A.y));  // c1_0, c1_1
            float2 k2 = __half22float2(u2h2(A.z));  // c2_0, c2_1
            float2 k3 = __half22float2(u2h2(A.w));  // c0_2, c1_2
            float  c22 = __half2float(__low2half(u2h2(Bv)));
            acc0 += fmaf(fmaf(k2.x, xl, k1.x), xl, k0.x);
            acc1 += fmaf(fmaf(k2.y, xl, k1.y), xl, k0.y);
            acc2 += fmaf(fmaf(c22,  xl, k3.y), xl, k3.x);
        }

        float* op = out + ((b * 3) << 18) + p;
        op[0]       = acc0;
        op[1 << 18] = acc1;
        op[2 << 18] = acc2;
    }
}

extern "C" void kernel_launch(void* const* d_in, const int* in_sizes, int n_in,
                              void* d_out, int out_size, void* d_ws, size_t ws_size,
                              hipStream_t stream) {
    const float* x  = (const float*)d_in[0]; // [8,3,512,512]
    const float* Wt = (const float*)d_in[1]; // [4,3,3,129]
    float* out = (float*)d_out;              // [8,3,512,512]

    hipLaunchKernelGGL(stripe_all, dim3(NBLK), dim3(256), 0, stream, x, Wt, out);
}

// Round 10
// 83.333 us; speedup vs baseline: 1.0934x; 1.0011x over previous
//
#include <hip/hip_runtime.h>
#include <hip/hip_fp16.h>
#include <math.h>

// StripePolynomial2d, round 10: R9 + v_fma_mix_f32 Horner.
// Phase C converts each f16 coeff at its point of use so LLVM's mad-mix pass
// folds cvt into v_fma_mix_f32: 3 VALU per output instead of 6 (-81/thread).
// Arithmetic bit-identical to R9 (f16->f32 cvt exact, f32 fma unchanged).
// Everything else identical to R9: split LDS tables (uint4[576] + uint[576]),
// __launch_bounds__(256,8), grid-stride persistent blocks.

#define NREC 576              // 9 ec * 64 seg
#define NTILE 8192            // 8 imgs * 1024 tiles
#define NBLK 2048

__device__ __forceinline__ __half2 u2h2(unsigned int u) {
    __half2 h; __builtin_memcpy(&h, &u, 4); return h;
}
__device__ __forceinline__ unsigned int h22u(__half2 h) {
    unsigned int u; __builtin_memcpy(&u, &h, 4); return u;
}
// f32 value of low/high half of a packed u32 — single-use so the compiler can
// fold the conversion into v_fma_mix_f32 (op_sel selects the half).
__device__ __forceinline__ float hlo(unsigned int u) {
    return __half2float(__low2half(u2h2(u)));
}
__device__ __forceinline__ float hhi(unsigned int u) {
    return __half2float(__high2half(u2h2(u)));
}

__device__ __forceinline__ void coeff_compute(const float* __restrict__ Wt, int r,
                                              uint4& a, unsigned int& bb) {
    int ec  = r >> 6;
    int seg = r & 63;
    int e   = ec / 3;
    int c   = ec - e * 3;
    int nb  = 2 * seg;
    float c0[3], c1[3], c2[3];
    #pragma unroll
    for (int o = 0; o < 3; ++o) {
        float w0, w1, w2;
        if (e == 0) {
            const float* p0 = Wt + ((0 * 3 + o) * 3 + c) * 129 + nb;
            const float* p1 = Wt + ((1 * 3 + o) * 3 + c) * 129 + nb;
            w0 = p0[0] + p1[0]; w1 = p0[1] + p1[1]; w2 = p0[2] + p1[2];
        } else {
            const float* p = Wt + (((e + 1) * 3 + o) * 3 + c) * 129 + nb;
            w0 = p[0]; w1 = p[1]; w2 = p[2];
        }
        c0[o] = 0.25f  * w1;
        c1[o] = 0.125f * (w2 - w0);
        c2[o] = 0.125f * (w0 + w2) - 0.25f * w1;
    }
    a.x = h22u(__floats2half2_rn(c0[0], c0[1]));
    a.y = h22u(__floats2half2_rn(c1[0], c1[1]));
    a.z = h22u(__floats2half2_rn(c2[0], c2[1]));
    a.w = h22u(__floats2half2_rn(c0[2], c1[2]));
    bb  = h22u(__floats2half2_rn(c2[2], 0.0f));
}

__global__ __launch_bounds__(256, 8) void stripe_all(
    const float* __restrict__ x, const float* __restrict__ Wt,
    float* __restrict__ out)
{
    __shared__ uint4        lwA[NREC];   // 9216 B
    __shared__ unsigned int lwB[NREC];   // 2304 B
    const int tid = threadIdx.x;

    // ---- build coeff table once per block ----
    for (int r = tid; r < NREC; r += 256) {
        uint4 a; unsigned int bb;
        coeff_compute(Wt, r, a, bb);
        lwA[r] = a;
        lwB[r] = bb;
    }
    __syncthreads();

    // q_e = pos_e/8 + 32, f32 from compile-time f64 constants.
    constexpr double RATIO = 512.0 / 513.0;
    constexpr double CX = 0x1.6a09e667f3bcdp-1;  // cos(f64 pi/4)
    constexpr double SY = 0x1.6a09e667f3bccp-1;  // sin(f64 pi/4), 1 ulp lower
    constexpr double S0 = RATIO * 64.0 / 511.0;
    constexpr double R2MAX = CX * 511.0 + SY * 511.0;
    constexpr double S2 = RATIO * 64.0 / R2MAX;
    constexpr double MN3 = -(SY * 511.0);
    constexpr double MX3 = CX * 511.0;
    constexpr double S3 = RATIO * 64.0 / (MX3 - MN3);

    for (int t = blockIdx.x; t < NTILE; t += NBLK) {
        const int b = t >> 10;
        const int p = ((t & 1023) << 8) + tid;
        const int w = p >> 9;
        const int h = p & 511;

        const float wf = (float)w, hf = (float)h;
        float qe[3];
        qe[0] = wf * (float)S0;
        qe[1] = fmaf(hf, (float)(SY * S2), wf * (float)(CX * S2));
        qe[2] = fmaf(hf, (float)(-(SY * S3)),
                     fmaf(wf, (float)(CX * S3), (float)(-MN3 * S3)));

        const int xbase = ((b * 3) << 18) + p;
        float xv[3];
        xv[0] = x[xbase];
        xv[1] = x[xbase + (1 << 18)];
        xv[2] = x[xbase + (2 << 18)];

        float acc0 = 0.f, acc1 = 0.f, acc2 = 0.f;

        #pragma unroll
        for (int s = 0; s < 9; ++s) {
            const int e = s / 3, c = s - 3 * (s / 3);
            float tn   = fmaf(xv[c], 0.125f, qe[e]);
            float segf = fminf(fmaxf(floorf(tn), 0.0f), 63.0f);
            int   seg  = (int)segf;
            float xl   = fmaf(tn - segf, 2.0f, -1.0f);

            const int  ri = s * 64 + seg;
            uint4        A  = lwA[ri];   // ds_read_b128
            unsigned int Bv = lwB[ri];   // ds_read_b32

            // Horner via fma_mix: each f16 coeff converted at point of use.
            acc0 += fmaf(fmaf(hlo(A.z), xl, hlo(A.y)), xl, hlo(A.x));
            acc1 += fmaf(fmaf(hhi(A.z), xl, hhi(A.y)), xl, hhi(A.x));
            acc2 += fmaf(fmaf(hlo(Bv),  xl, hhi(A.w)), xl, hlo(A.w));
        }

        float* op = out + ((b * 3) << 18) + p;
        op[0]       = acc0;
        op[1 << 18] = acc1;
        op[2 << 18] = acc2;
    }
}

extern "C" void kernel_launch(void* const* d_in, const int* in_sizes, int n_in,
                              void* d_out, int out_size, void* d_ws, size_t ws_size,
                              hipStream_t stream) {
    const float* x  = (const float*)d_in[0]; // [8,3,512,512]
    const float* Wt = (const float*)d_in[1]; // [4,3,3,129]
    float* out = (float*)d_out;              // [8,3,512,512]

    hipLaunchKernelGGL(stripe_all, dim3(NBLK), dim3(256), 0, stream, x, Wt, out);
}